// Round 11
// baseline (74.965 us; speedup 1.0000x reference)
//
#include <hip/hip_runtime.h>
#include <hip/hip_bf16.h>

#define BB 8
#define HH 64
#define WW 64
#define DD 128
#define NH 4
#define HD 32
#define KS 7
#define TS 8
#define HALO 14   // TS + KS - 1

typedef __attribute__((ext_vector_type(8))) short short8v;   // 8 bf16
typedef __attribute__((ext_vector_type(4))) short short4v;   // 4 bf16
typedef __attribute__((ext_vector_type(4))) float f32x4;
typedef unsigned short bf16_t;

__device__ inline short f2bf(float f) {   // fp32 -> bf16 RNE
  union { float f; unsigned u; } x; x.f = f;
  unsigned r = x.u + 0x7FFFu + ((x.u >> 16) & 1u);
  return (short)(r >> 16);
}

// ---------------------------------------------------------------------------
// GEMM #1: qkv = x(32768,128) @ w_qkv^T + b -> q,k,v bf16 [B][NH][HW][HD],
// softmax scale pre-folded into q.  LDS-staged coalesced epilogue.
// (byte-identical to round 10 — do not perturb the ablation)
// ---------------------------------------------------------------------------
__global__ __launch_bounds__(256) void qkv_mfma(
    const float* __restrict__ x, const float* __restrict__ w,
    const float* __restrict__ bqkv,
    bf16_t* __restrict__ q, bf16_t* __restrict__ k, bf16_t* __restrict__ v) {
  __shared__ __align__(16) short smA[128 * 128];
  __shared__ __align__(16) short smB[128 * 128];
  const int tid = threadIdx.x;
  const int m_tile = blockIdx.x;   // 0..255
  const int n_tile = blockIdx.y;   // 0..2  (0=q 1=k 2=v)

  const float* Ab = x + (size_t)m_tile * 128 * 128;
  const float* Bb = w + (size_t)n_tile * 128 * 128;
#pragma unroll
  for (int i = 0; i < 8; i++) {
    int idx = tid + i * 256;
    int r = idx >> 4, p = idx & 15;
    const float* ap = Ab + r * 128 + p * 8;
    float4 a0 = *(const float4*)ap;
    float4 a1 = *(const float4*)(ap + 4);
    short8v s;
    s[0] = f2bf(a0.x); s[1] = f2bf(a0.y); s[2] = f2bf(a0.z); s[3] = f2bf(a0.w);
    s[4] = f2bf(a1.x); s[5] = f2bf(a1.y); s[6] = f2bf(a1.z); s[7] = f2bf(a1.w);
    *(short8v*)((char*)smA + ((r * 256 + p * 16) ^ ((r & 7) << 4))) = s;
    const float* bp_ = Bb + r * 128 + p * 8;
    float4 b0 = *(const float4*)bp_;
    float4 b1 = *(const float4*)(bp_ + 4);
    short8v t;
    t[0] = f2bf(b0.x); t[1] = f2bf(b0.y); t[2] = f2bf(b0.z); t[3] = f2bf(b0.w);
    t[4] = f2bf(b1.x); t[5] = f2bf(b1.y); t[6] = f2bf(b1.z); t[7] = f2bf(b1.w);
    *(short8v*)((char*)smB + ((r * 256 + p * 16) ^ ((r & 7) << 4))) = t;
  }
  __syncthreads();

  const int lane = tid & 63;
  const int wid = tid >> 6;
  const int wm = wid >> 1, wn = wid & 1;
  const int l15 = lane & 15, l4 = lane >> 4;

  f32x4 acc[4][4] = {};
  const int rowA0 = wm * 64 + l15;
  const int rowB0 = wn * 64 + l15;
  const int swzA = (rowA0 & 7) << 4;
  const int swzB = (rowB0 & 7) << 4;

#pragma unroll
  for (int ks = 0; ks < 4; ks++) {
    const int cb = ks * 64 + l4 * 16;
    short8v a[4], b[4];
#pragma unroll
    for (int i = 0; i < 4; i++) {
      a[i] = *(const short8v*)((const char*)smA + ((((rowA0 + i * 16) * 256) + cb) ^ swzA));
      b[i] = *(const short8v*)((const char*)smB + ((((rowB0 + i * 16) * 256) + cb) ^ swzB));
    }
#pragma unroll
    for (int mi = 0; mi < 4; mi++)
#pragma unroll
      for (int nj = 0; nj < 4; nj++)
        acc[mi][nj] = __builtin_amdgcn_mfma_f32_16x16x32_bf16(a[mi], b[nj], acc[mi][nj], 0, 0, 0);
  }

  // ---- epilogue: bias+scale -> bf16 C-tile in LDS (smA dead) -> coalesced out
  __syncthreads();
  short* smC = smA;   // [128 m][128 n] bf16, swz ((m&7)<<4)
  const float qscale = 0.17677669529663687f;  // 1/sqrt(32)
#pragma unroll
  for (int nj = 0; nj < 4; nj++) {
    const int n_local = wn * 64 + nj * 16 + l15;
    const int n = n_tile * 128 + n_local;
    const float bias = bqkv[n];
    const float sc = (n_tile == 0) ? qscale : 1.f;
#pragma unroll
    for (int mi = 0; mi < 4; mi++) {
#pragma unroll
      for (int r = 0; r < 4; r++) {
        const int m = wm * 64 + mi * 16 + l4 * 4 + r;
        *(bf16_t*)((char*)smC + ((m * 256 + n_local * 2) ^ ((m & 7) << 4))) =
            (bf16_t)f2bf((acc[mi][nj][r] + bias) * sc);
      }
    }
  }
  __syncthreads();

  const int bblk = m_tile >> 5;
  bf16_t* outp = (n_tile == 0) ? q : ((n_tile == 1) ? k : v);
#pragma unroll
  for (int i = 0; i < 8; i++) {
    const int idx = i * 256 + tid;         // 0..2047
    const int h = idx >> 9;                // head plane
    const int rem = idx & 511;
    const int m = rem >> 2, c = rem & 3;   // pixel row, 16B chunk
    short8v t8 = *(const short8v*)((const char*)smC +
        ((m * 256 + h * 64 + c * 16) ^ ((m & 7) << 4)));
    const int pix = (m_tile * 128 + m) & 4095;
    *(short8v*)(outp + ((size_t)(bblk * 4 + h)) * 131072 + (size_t)pix * 32 + c * 8) = t8;
  }
}

// ---------------------------------------------------------------------------
// Kernel 2: MFMA neighborhood attention, K-LDS-free (round-10, unchanged).
// ABLATION NOTE: kernel_launch launches this 3x this round.  It reads q,k,v
// (never modified) and fully overwrites ao deterministically -> idempotent;
// dur_us delta vs round 10 = 2*(attn + launch overhead).
// ---------------------------------------------------------------------------
__global__ __launch_bounds__(256) void attn_mfma(
    const bf16_t* __restrict__ q, const bf16_t* __restrict__ k,
    const bf16_t* __restrict__ v, bf16_t* __restrict__ ao) {
  // vtb: [32 d][512 B]  swz ((d&7)<<4), cols = 224 pos + 32 pad
  __shared__ __align__(16) char vtb[16384];

  const int tile = blockIdx.x;
  const int tx = tile >> 3, ty = tile & 7;
  const int head = blockIdx.y, bb = blockIdx.z;
  const size_t bh = ((size_t)bb * NH + head) * 4096;
  const bf16_t* kb = k + bh * HD;
  const bf16_t* vb = v + bh * HD;
  const bf16_t* qb = q + bh * HD;
  const int rstart = min(max(tx * TS - 3, 0), HH - HALO);
  const int cstart = min(max(ty * TS - 3, 0), WW - HALO);
  const int tid = threadIdx.x;
  const int lane = tid & 63, wid = tid >> 6;
  const int l15 = lane & 15, h4 = lane >> 4;

  // Q fragment (B-operand: col = q = l15, k-chunk h4*8); pre-scaled in qkv
  short8v qf;
  int qx, qy;
  {
    const int pit = wid * 16 + l15;
    qx = tx * TS + (pit >> 3);
    qy = ty * TS + (pit & 7);
    qf = *(const short8v*)(qb + ((size_t)(qx * WW + qy)) * HD + h4 * 8);
  }
  const int wx0 = min(max(qx - 3, 0), HH - KS) - rstart;
  const int wy0 = min(max(qy - 3, 0), WW - KS) - cstart;

  // wave-uniform even base row (wave covers pixel rows tx*8+wid*2, +1)
  const int x0 = tx * TS + wid * 2;
  const int w0 = min(max(x0 - 3, 0), HH - KS) - rstart;
  const int base = min(w0 & ~1, 4);        // halo rows base..base+9 cover all lanes

  // ---- issue V loads into registers (consumed after QK^T)
  short4v vl[4][2];
#pragma unroll
  for (int t = 0; t < 4; t++) {
    const int idx = tid + t * 256;
    if (idx < 784) {
      const int pp = idx >> 3, c = idx & 7;
      const int pr = pp / 7, pc2 = (pp % 7) * 2;
      const size_t g = ((size_t)((rstart + pr) * WW + (cstart + pc2))) * HD + c * 4;
      vl[t][0] = *(const short4v*)(vb + g);
      vl[t][1] = *(const short4v*)(vb + g + HD);
    }
  }

  // ---- S^T = K.Q^T, K streamed from global (coalesced per nt)
  f32x4 acc[10];
  const f32x4 zf = {0.f, 0.f, 0.f, 0.f};
  const int kcol = cstart + min(l15, 13);   // clamp garbage cols (masked later)
#pragma unroll
  for (int ch = 0; ch < 2; ch++) {
    short8v kf[5];
#pragma unroll
    for (int i = 0; i < 5; i++) {
      const int pr = rstart + base + ch * 5 + i;
      kf[i] = *(const short8v*)(kb + ((size_t)(pr * WW + kcol)) * HD + h4 * 8);
    }
    __builtin_amdgcn_s_setprio(1);
#pragma unroll
    for (int i = 0; i < 5; i++)
      acc[ch * 5 + i] = __builtin_amdgcn_mfma_f32_16x16x32_bf16(kf[i], qf, zf, 0, 0, 0);
    __builtin_amdgcn_s_setprio(0);
  }

  // ---- pack + write V^T to LDS (pos remap), zero pad cols
#pragma unroll
  for (int t = 0; t < 4; t++) {
    const int idx = tid + t * 256;
    if (idx < 784) {
      const int pp = idx >> 3, c = idx & 7;
      const int pr = pp / 7, pc2 = (pp % 7) * 2;
      const int pos0 = ((pr >> 1) << 5) + ((pc2 >> 2) << 3) + ((pr & 1) << 2) + (pc2 & 3);
#pragma unroll
      for (int j = 0; j < 4; j++) {
        const int d = c * 4 + j;
        const unsigned pk2 = (unsigned)(unsigned short)vl[t][0][j] |
                             ((unsigned)(unsigned short)vl[t][1][j] << 16);
        *(unsigned*)(vtb + ((d * 512 + pos0 * 2) ^ ((d & 7) << 4))) = pk2;
      }
    }
  }
  for (int idx = tid; idx < 512; idx += 256) {
    const int d = idx >> 4, pr = idx & 15;
    if (pr < 14) {
      const int pos = ((pr >> 1) << 5) + 24 + ((pr & 1) << 2) + 2;  // nc 14,15
      *(unsigned*)(vtb + ((d * 512 + pos * 2) ^ ((d & 7) << 4))) = 0u;
    }
  }
  __syncthreads();

  // ---- mask + no-max softmax (masked -> exact 0), all in registers
  bool cv[4];
#pragma unroll
  for (int r = 0; r < 4; r++) cv[r] = ((unsigned)(h4 * 4 + r - wy0) < 7u);
  float sum = 0.f;
#pragma unroll
  for (int nt = 0; nt < 10; nt++) {
    const bool rv = ((unsigned)(base + nt - wx0) < 7u);
#pragma unroll
    for (int r = 0; r < 4; r++) {
      const float p = (rv && cv[r]) ? __expf(acc[nt][r]) : 0.f;
      acc[nt][r] = p;
      sum += p;
    }
  }
  sum += __shfl_xor(sum, 16);
  sum += __shfl_xor(sum, 32);
  const float inv = 1.f / sum;

  // ---- O = P.V over the 5 k-chunks; P normalized+packed in the loop
  f32x4 o0 = zf, o1 = zf;
  const int swzv = (l15 & 7) << 4;
  const int cbase = (base >> 1) * 64;
  __builtin_amdgcn_s_setprio(1);
#pragma unroll
  for (int kc = 0; kc < 5; kc++) {
    union { unsigned u[4]; short8v s; } pa;
    pa.u[0] = (unsigned)(unsigned short)f2bf(acc[2 * kc][0] * inv) |
              ((unsigned)(unsigned short)f2bf(acc[2 * kc][1] * inv) << 16);
    pa.u[1] = (unsigned)(unsigned short)f2bf(acc[2 * kc][2] * inv) |
              ((unsigned)(unsigned short)f2bf(acc[2 * kc][3] * inv) << 16);
    pa.u[2] = (unsigned)(unsigned short)f2bf(acc[2 * kc + 1][0] * inv) |
              ((unsigned)(unsigned short)f2bf(acc[2 * kc + 1][1] * inv) << 16);
    pa.u[3] = (unsigned)(unsigned short)f2bf(acc[2 * kc + 1][2] * inv) |
              ((unsigned)(unsigned short)f2bf(acc[2 * kc + 1][3] * inv) << 16);
    const int boff = cbase + kc * 64 + h4 * 16;
    short8v vb0 = *(const short8v*)(vtb + ((l15 * 512 + boff) ^ swzv));
    short8v vb1 = *(const short8v*)(vtb + (((l15 + 16) * 512 + boff) ^ swzv));
    o0 = __builtin_amdgcn_mfma_f32_16x16x32_bf16(pa.s, vb0, o0, 0, 0, 0);
    o1 = __builtin_amdgcn_mfma_f32_16x16x32_bf16(pa.s, vb1, o1, 0, 0, 0);
  }
  __builtin_amdgcn_s_setprio(0);

  // ---- epilogue: lane (l15,h4) holds O[q=h4*4+r][d=l15(+16)], normalized
#pragma unroll
  for (int r = 0; r < 4; r++) {
    const int pit = wid * 16 + h4 * 4 + r;
    const int x = tx * TS + (pit >> 3), y = ty * TS + (pit & 7);
    bf16_t* op = ao + ((size_t)bb * 4096 + x * WW + y) * DD + head * HD;
    op[l15]      = (bf16_t)f2bf(o0[r]);
    op[l15 + 16] = (bf16_t)f2bf(o1[r]);
  }
}

// ---------------------------------------------------------------------------
// GEMM #2: out = ao(32768,128 bf16) @ w_proj^T + b -> d_out fp32.
// (byte-identical to round 10)
// ---------------------------------------------------------------------------
__global__ __launch_bounds__(256) void proj_mfma(
    const bf16_t* __restrict__ aob, const float* __restrict__ wp,
    const float* __restrict__ bp, float* __restrict__ out) {
  __shared__ __align__(16) char plds[65536];
  short* smA = (short*)plds;
  short* smB = (short*)(plds + 32768);
  const int tid = threadIdx.x;
  const int m_tile = blockIdx.x;   // 0..255

  const bf16_t* Ab = aob + (size_t)m_tile * 128 * 128;
#pragma unroll
  for (int i = 0; i < 8; i++) {
    int idx = tid + i * 256;
    int r = idx >> 4, p = idx & 15;
    short8v s = *(const short8v*)(Ab + r * 128 + p * 8);
    *(short8v*)((char*)smA + ((r * 256 + p * 16) ^ ((r & 7) << 4))) = s;
    const float* bp_ = wp + r * 128 + p * 8;
    float4 b0 = *(const float4*)bp_;
    float4 b1 = *(const float4*)(bp_ + 4);
    short8v t;
    t[0] = f2bf(b0.x); t[1] = f2bf(b0.y); t[2] = f2bf(b0.z); t[3] = f2bf(b0.w);
    t[4] = f2bf(b1.x); t[5] = f2bf(b1.y); t[6] = f2bf(b1.z); t[7] = f2bf(b1.w);
    *(short8v*)((char*)smB + ((r * 256 + p * 16) ^ ((r & 7) << 4))) = t;
  }
  __syncthreads();

  const int lane = tid & 63;
  const int wid = tid >> 6;
  const int wm = wid >> 1, wn = wid & 1;
  const int l15 = lane & 15, l4 = lane >> 4;

  f32x4 acc[4][4] = {};
  const int rowA0 = wm * 64 + l15;
  const int rowB0 = wn * 64 + l15;
  const int swzA = (rowA0 & 7) << 4;
  const int swzB = (rowB0 & 7) << 4;

#pragma unroll
  for (int ks = 0; ks < 4; ks++) {
    const int cb = ks * 64 + l4 * 16;
    short8v a[4], b[4];
#pragma unroll
    for (int i = 0; i < 4; i++) {
      a[i] = *(const short8v*)((const char*)smA + ((((rowA0 + i * 16) * 256) + cb) ^ swzA));
      b[i] = *(const short8v*)((const char*)smB + ((((rowB0 + i * 16) * 256) + cb) ^ swzB));
    }
#pragma unroll
    for (int mi = 0; mi < 4; mi++)
#pragma unroll
      for (int nj = 0; nj < 4; nj++)
        acc[mi][nj] = __builtin_amdgcn_mfma_f32_16x16x32_bf16(a[mi], b[nj], acc[mi][nj], 0, 0, 0);
  }

  // ---- epilogue: bias -> fp32 C-tile in LDS -> coalesced float4 stores
  __syncthreads();
#pragma unroll
  for (int nj = 0; nj < 4; nj++) {
    const int n = wn * 64 + nj * 16 + l15;
    const float bias = bp[n];
#pragma unroll
    for (int mi = 0; mi < 4; mi++) {
#pragma unroll
      for (int r = 0; r < 4; r++) {
        const int m = wm * 64 + mi * 16 + l4 * 4 + r;
        *(float*)(plds + ((m * 512 + n * 4) ^ ((m & 7) << 5))) = acc[mi][nj][r] + bias;
      }
    }
  }
  __syncthreads();

#pragma unroll
  for (int i = 0; i < 16; i++) {
    const int idx = i * 256 + tid;         // 0..4095
    const int m = idx >> 5, c = idx & 31;  // row, float4 chunk
    float4 t = *(const float4*)(plds + ((m * 512 + c * 16) ^ ((m & 7) << 5)));
    *(float4*)(out + (size_t)(m_tile * 128 + m) * DD + c * 4) = t;
  }
}

// ---------------------------------------------------------------------------
extern "C" void kernel_launch(void* const* d_in, const int* in_sizes, int n_in,
                              void* d_out, int out_size, void* d_ws, size_t ws_size,
                              hipStream_t stream) {
  const float* x      = (const float*)d_in[0];
  const float* w_qkv  = (const float*)d_in[1];
  const float* b_qkv  = (const float*)d_in[2];
  const float* w_proj = (const float*)d_in[3];
  const float* b_proj = (const float*)d_in[4];
  float* out = (float*)d_out;

  const size_t per = (size_t)BB * NH * HH * WW * HD;  // 4,194,304 elements
  bf16_t* q  = (bf16_t*)d_ws;
  bf16_t* k  = q + per;
  bf16_t* v  = k + per;
  bf16_t* ao = v + per;   // 32 MB bf16 workspace

  qkv_mfma<<<dim3(256, 3), dim3(256), 0, stream>>>(x, w_qkv, b_qkv, q, k, v);
  // ABLATION (this round only): attn launched 3x.  Idempotent — reads q,k,v
  // (unmodified) and fully overwrites ao with identical values each time.
  // R11_dur - R10_dur = 2*(attn_dur + launch_overhead).
  attn_mfma<<<dim3(64, NH, BB), dim3(256), 0, stream>>>(q, k, v, ao);
  attn_mfma<<<dim3(64, NH, BB), dim3(256), 0, stream>>>(q, k, v, ao);
  attn_mfma<<<dim3(64, NH, BB), dim3(256), 0, stream>>>(q, k, v, ao);
  proj_mfma<<<dim3(256), dim3(256), 0, stream>>>(ao, w_proj, b_proj, out);
}

// Round 12
// 43.743 us; speedup vs baseline: 1.7138x; 1.7138x over previous
//
#include <hip/hip_runtime.h>
#include <hip/hip_bf16.h>

#define BB 8
#define HH 64
#define WW 64
#define DD 128
#define NH 4
#define HD 32
#define KS 7
#define TS 8
#define HALO 14   // TS + KS - 1

typedef __attribute__((ext_vector_type(8))) short short8v;   // 8 bf16
typedef __attribute__((ext_vector_type(4))) short short4v;   // 4 bf16
typedef __attribute__((ext_vector_type(4))) float f32x4;
typedef unsigned short bf16_t;

// fp32 -> bf16 via the NATIVE cast: compiler fuses adjacent casts into
// v_cvt_pk_bf16_f32 (1 inst / 2 floats).  The former hand-rolled RNE bit
// sequence (~5 VALU inst each) cost ~640 VALU inst/thread in qkv staging.
__device__ inline bf16_t f2bf(float f) {
  __hip_bfloat16 h = __float2bfloat16(f);
  return *reinterpret_cast<bf16_t*>(&h);
}

// ---------------------------------------------------------------------------
// GEMM #1: qkv = x(32768,128) @ w_qkv^T + b -> q,k,v bf16 [B][NH][HW][HD],
// softmax scale pre-folded into q.  LDS-staged coalesced epilogue.
// ---------------------------------------------------------------------------
__global__ __launch_bounds__(256) void qkv_mfma(
    const float* __restrict__ x, const float* __restrict__ w,
    const float* __restrict__ bqkv,
    bf16_t* __restrict__ q, bf16_t* __restrict__ k, bf16_t* __restrict__ v) {
  __shared__ __align__(16) short smA[128 * 128];
  __shared__ __align__(16) short smB[128 * 128];
  const int tid = threadIdx.x;
  const int m_tile = blockIdx.x;   // 0..255
  const int n_tile = blockIdx.y;   // 0..2  (0=q 1=k 2=v)

  const float* Ab = x + (size_t)m_tile * 128 * 128;
  const float* Bb = w + (size_t)n_tile * 128 * 128;
#pragma unroll
  for (int i = 0; i < 8; i++) {
    int idx = tid + i * 256;
    int r = idx >> 4, p = idx & 15;
    const float* ap = Ab + r * 128 + p * 8;
    float4 a0 = *(const float4*)ap;
    float4 a1 = *(const float4*)(ap + 4);
    short8v s;
    s[0] = f2bf(a0.x); s[1] = f2bf(a0.y); s[2] = f2bf(a0.z); s[3] = f2bf(a0.w);
    s[4] = f2bf(a1.x); s[5] = f2bf(a1.y); s[6] = f2bf(a1.z); s[7] = f2bf(a1.w);
    *(short8v*)((char*)smA + ((r * 256 + p * 16) ^ ((r & 7) << 4))) = s;
    const float* bp_ = Bb + r * 128 + p * 8;
    float4 b0 = *(const float4*)bp_;
    float4 b1 = *(const float4*)(bp_ + 4);
    short8v t;
    t[0] = f2bf(b0.x); t[1] = f2bf(b0.y); t[2] = f2bf(b0.z); t[3] = f2bf(b0.w);
    t[4] = f2bf(b1.x); t[5] = f2bf(b1.y); t[6] = f2bf(b1.z); t[7] = f2bf(b1.w);
    *(short8v*)((char*)smB + ((r * 256 + p * 16) ^ ((r & 7) << 4))) = t;
  }
  __syncthreads();

  const int lane = tid & 63;
  const int wid = tid >> 6;
  const int wm = wid >> 1, wn = wid & 1;
  const int l15 = lane & 15, l4 = lane >> 4;

  f32x4 acc[4][4] = {};
  const int rowA0 = wm * 64 + l15;
  const int rowB0 = wn * 64 + l15;
  const int swzA = (rowA0 & 7) << 4;
  const int swzB = (rowB0 & 7) << 4;

#pragma unroll
  for (int ks = 0; ks < 4; ks++) {
    const int cb = ks * 64 + l4 * 16;
    short8v a[4], b[4];
#pragma unroll
    for (int i = 0; i < 4; i++) {
      a[i] = *(const short8v*)((const char*)smA + ((((rowA0 + i * 16) * 256) + cb) ^ swzA));
      b[i] = *(const short8v*)((const char*)smB + ((((rowB0 + i * 16) * 256) + cb) ^ swzB));
    }
#pragma unroll
    for (int mi = 0; mi < 4; mi++)
#pragma unroll
      for (int nj = 0; nj < 4; nj++)
        acc[mi][nj] = __builtin_amdgcn_mfma_f32_16x16x32_bf16(a[mi], b[nj], acc[mi][nj], 0, 0, 0);
  }

  // ---- epilogue: bias+scale -> bf16 C-tile in LDS (smA dead) -> coalesced out
  __syncthreads();
  short* smC = smA;   // [128 m][128 n] bf16, swz ((m&7)<<4)
  const float qscale = 0.17677669529663687f;  // 1/sqrt(32)
#pragma unroll
  for (int nj = 0; nj < 4; nj++) {
    const int n_local = wn * 64 + nj * 16 + l15;
    const int n = n_tile * 128 + n_local;
    const float bias = bqkv[n];
    const float sc = (n_tile == 0) ? qscale : 1.f;
#pragma unroll
    for (int mi = 0; mi < 4; mi++) {
#pragma unroll
      for (int r = 0; r < 4; r++) {
        const int m = wm * 64 + mi * 16 + l4 * 4 + r;
        *(bf16_t*)((char*)smC + ((m * 256 + n_local * 2) ^ ((m & 7) << 4))) =
            (bf16_t)f2bf((acc[mi][nj][r] + bias) * sc);
      }
    }
  }
  __syncthreads();

  const int bblk = m_tile >> 5;
  bf16_t* outp = (n_tile == 0) ? q : ((n_tile == 1) ? k : v);
#pragma unroll
  for (int i = 0; i < 8; i++) {
    const int idx = i * 256 + tid;         // 0..2047
    const int h = idx >> 9;                // head plane
    const int rem = idx & 511;
    const int m = rem >> 2, c = rem & 3;   // pixel row, 16B chunk
    short8v t8 = *(const short8v*)((const char*)smC +
        ((m * 256 + h * 64 + c * 16) ^ ((m & 7) << 4)));
    const int pix = (m_tile * 128 + m) & 4095;
    *(short8v*)(outp + ((size_t)(bblk * 4 + h)) * 131072 + (size_t)pix * 32 + c * 8) = t8;
  }
}

// ---------------------------------------------------------------------------
// Kernel 2: MFMA neighborhood attention, K-LDS-free (round-10 structure).
// ---------------------------------------------------------------------------
__global__ __launch_bounds__(256) void attn_mfma(
    const bf16_t* __restrict__ q, const bf16_t* __restrict__ k,
    const bf16_t* __restrict__ v, bf16_t* __restrict__ ao) {
  // vtb: [32 d][512 B]  swz ((d&7)<<4), cols = 224 pos + 32 pad
  __shared__ __align__(16) char vtb[16384];

  const int tile = blockIdx.x;
  const int tx = tile >> 3, ty = tile & 7;
  const int head = blockIdx.y, bb = blockIdx.z;
  const size_t bh = ((size_t)bb * NH + head) * 4096;
  const bf16_t* kb = k + bh * HD;
  const bf16_t* vb = v + bh * HD;
  const bf16_t* qb = q + bh * HD;
  const int rstart = min(max(tx * TS - 3, 0), HH - HALO);
  const int cstart = min(max(ty * TS - 3, 0), WW - HALO);
  const int tid = threadIdx.x;
  const int lane = tid & 63, wid = tid >> 6;
  const int l15 = lane & 15, h4 = lane >> 4;

  // Q fragment (B-operand: col = q = l15, k-chunk h4*8); pre-scaled in qkv
  short8v qf;
  int qx, qy;
  {
    const int pit = wid * 16 + l15;
    qx = tx * TS + (pit >> 3);
    qy = ty * TS + (pit & 7);
    qf = *(const short8v*)(qb + ((size_t)(qx * WW + qy)) * HD + h4 * 8);
  }
  const int wx0 = min(max(qx - 3, 0), HH - KS) - rstart;
  const int wy0 = min(max(qy - 3, 0), WW - KS) - cstart;

  // wave-uniform even base row (wave covers pixel rows tx*8+wid*2, +1)
  const int x0 = tx * TS + wid * 2;
  const int w0 = min(max(x0 - 3, 0), HH - KS) - rstart;
  const int base = min(w0 & ~1, 4);        // halo rows base..base+9 cover all lanes

  // ---- issue V loads into registers (consumed after QK^T)
  short4v vl[4][2];
#pragma unroll
  for (int t = 0; t < 4; t++) {
    const int idx = tid + t * 256;
    if (idx < 784) {
      const int pp = idx >> 3, c = idx & 7;
      const int pr = pp / 7, pc2 = (pp % 7) * 2;
      const size_t g = ((size_t)((rstart + pr) * WW + (cstart + pc2))) * HD + c * 4;
      vl[t][0] = *(const short4v*)(vb + g);
      vl[t][1] = *(const short4v*)(vb + g + HD);
    }
  }

  // ---- S^T = K.Q^T, K streamed from global (coalesced per nt)
  f32x4 acc[10];
  const f32x4 zf = {0.f, 0.f, 0.f, 0.f};
  const int kcol = cstart + min(l15, 13);   // clamp garbage cols (masked later)
#pragma unroll
  for (int ch = 0; ch < 2; ch++) {
    short8v kf[5];
#pragma unroll
    for (int i = 0; i < 5; i++) {
      const int pr = rstart + base + ch * 5 + i;
      kf[i] = *(const short8v*)(kb + ((size_t)(pr * WW + kcol)) * HD + h4 * 8);
    }
    __builtin_amdgcn_s_setprio(1);
#pragma unroll
    for (int i = 0; i < 5; i++)
      acc[ch * 5 + i] = __builtin_amdgcn_mfma_f32_16x16x32_bf16(kf[i], qf, zf, 0, 0, 0);
    __builtin_amdgcn_s_setprio(0);
  }

  // ---- pack + write V^T to LDS (pos remap), zero pad cols
#pragma unroll
  for (int t = 0; t < 4; t++) {
    const int idx = tid + t * 256;
    if (idx < 784) {
      const int pp = idx >> 3, c = idx & 7;
      const int pr = pp / 7, pc2 = (pp % 7) * 2;
      const int pos0 = ((pr >> 1) << 5) + ((pc2 >> 2) << 3) + ((pr & 1) << 2) + (pc2 & 3);
#pragma unroll
      for (int j = 0; j < 4; j++) {
        const int d = c * 4 + j;
        const unsigned pk2 = (unsigned)(unsigned short)vl[t][0][j] |
                             ((unsigned)(unsigned short)vl[t][1][j] << 16);
        *(unsigned*)(vtb + ((d * 512 + pos0 * 2) ^ ((d & 7) << 4))) = pk2;
      }
    }
  }
  for (int idx = tid; idx < 512; idx += 256) {
    const int d = idx >> 4, pr = idx & 15;
    if (pr < 14) {
      const int pos = ((pr >> 1) << 5) + 24 + ((pr & 1) << 2) + 2;  // nc 14,15
      *(unsigned*)(vtb + ((d * 512 + pos * 2) ^ ((d & 7) << 4))) = 0u;
    }
  }
  __syncthreads();

  // ---- mask + no-max softmax (masked -> exact 0), all in registers
  bool cv[4];
#pragma unroll
  for (int r = 0; r < 4; r++) cv[r] = ((unsigned)(h4 * 4 + r - wy0) < 7u);
  float sum = 0.f;
#pragma unroll
  for (int nt = 0; nt < 10; nt++) {
    const bool rv = ((unsigned)(base + nt - wx0) < 7u);
#pragma unroll
    for (int r = 0; r < 4; r++) {
      const float p = (rv && cv[r]) ? __expf(acc[nt][r]) : 0.f;
      acc[nt][r] = p;
      sum += p;
    }
  }
  sum += __shfl_xor(sum, 16);
  sum += __shfl_xor(sum, 32);
  const float inv = 1.f / sum;

  // ---- O = P.V over the 5 k-chunks; P normalized+packed in the loop
  f32x4 o0 = zf, o1 = zf;
  const int swzv = (l15 & 7) << 4;
  const int cbase = (base >> 1) * 64;
  __builtin_amdgcn_s_setprio(1);
#pragma unroll
  for (int kc = 0; kc < 5; kc++) {
    union { unsigned u[4]; short8v s; } pa;
    pa.u[0] = (unsigned)f2bf(acc[2 * kc][0] * inv) |
              ((unsigned)f2bf(acc[2 * kc][1] * inv) << 16);
    pa.u[1] = (unsigned)f2bf(acc[2 * kc][2] * inv) |
              ((unsigned)f2bf(acc[2 * kc][3] * inv) << 16);
    pa.u[2] = (unsigned)f2bf(acc[2 * kc + 1][0] * inv) |
              ((unsigned)f2bf(acc[2 * kc + 1][1] * inv) << 16);
    pa.u[3] = (unsigned)f2bf(acc[2 * kc + 1][2] * inv) |
              ((unsigned)f2bf(acc[2 * kc + 1][3] * inv) << 16);
    const int boff = cbase + kc * 64 + h4 * 16;
    short8v vb0 = *(const short8v*)(vtb + ((l15 * 512 + boff) ^ swzv));
    short8v vb1 = *(const short8v*)(vtb + (((l15 + 16) * 512 + boff) ^ swzv));
    o0 = __builtin_amdgcn_mfma_f32_16x16x32_bf16(pa.s, vb0, o0, 0, 0, 0);
    o1 = __builtin_amdgcn_mfma_f32_16x16x32_bf16(pa.s, vb1, o1, 0, 0, 0);
  }
  __builtin_amdgcn_s_setprio(0);

  // ---- epilogue: lane (l15,h4) holds O[q=h4*4+r][d=l15(+16)], normalized
#pragma unroll
  for (int r = 0; r < 4; r++) {
    const int pit = wid * 16 + h4 * 4 + r;
    const int x = tx * TS + (pit >> 3), y = ty * TS + (pit & 7);
    bf16_t* op = ao + ((size_t)bb * 4096 + x * WW + y) * DD + head * HD;
    op[l15]      = (bf16_t)f2bf(o0[r]);
    op[l15 + 16] = (bf16_t)f2bf(o1[r]);
  }
}

// ---------------------------------------------------------------------------
// GEMM #2: out = ao(32768,128 bf16) @ w_proj^T + b -> d_out fp32.
// LDS-staged fp32 C epilogue -> contiguous float4 stores.
// ---------------------------------------------------------------------------
__global__ __launch_bounds__(256) void proj_mfma(
    const bf16_t* __restrict__ aob, const float* __restrict__ wp,
    const float* __restrict__ bp, float* __restrict__ out) {
  __shared__ __align__(16) char plds[65536];
  short* smA = (short*)plds;
  short* smB = (short*)(plds + 32768);
  const int tid = threadIdx.x;
  const int m_tile = blockIdx.x;   // 0..255

  const bf16_t* Ab = aob + (size_t)m_tile * 128 * 128;
#pragma unroll
  for (int i = 0; i < 8; i++) {
    int idx = tid + i * 256;
    int r = idx >> 4, p = idx & 15;
    short8v s = *(const short8v*)(Ab + r * 128 + p * 8);
    *(short8v*)((char*)smA + ((r * 256 + p * 16) ^ ((r & 7) << 4))) = s;
    const float* bp_ = wp + r * 128 + p * 8;
    float4 b0 = *(const float4*)bp_;
    float4 b1 = *(const float4*)(bp_ + 4);
    short8v t;
    t[0] = f2bf(b0.x); t[1] = f2bf(b0.y); t[2] = f2bf(b0.z); t[3] = f2bf(b0.w);
    t[4] = f2bf(b1.x); t[5] = f2bf(b1.y); t[6] = f2bf(b1.z); t[7] = f2bf(b1.w);
    *(short8v*)((char*)smB + ((r * 256 + p * 16) ^ ((r & 7) << 4))) = t;
  }
  __syncthreads();

  const int lane = tid & 63;
  const int wid = tid >> 6;
  const int wm = wid >> 1, wn = wid & 1;
  const int l15 = lane & 15, l4 = lane >> 4;

  f32x4 acc[4][4] = {};
  const int rowA0 = wm * 64 + l15;
  const int rowB0 = wn * 64 + l15;
  const int swzA = (rowA0 & 7) << 4;
  const int swzB = (rowB0 & 7) << 4;

#pragma unroll
  for (int ks = 0; ks < 4; ks++) {
    const int cb = ks * 64 + l4 * 16;
    short8v a[4], b[4];
#pragma unroll
    for (int i = 0; i < 4; i++) {
      a[i] = *(const short8v*)((const char*)smA + ((((rowA0 + i * 16) * 256) + cb) ^ swzA));
      b[i] = *(const short8v*)((const char*)smB + ((((rowB0 + i * 16) * 256) + cb) ^ swzB));
    }
#pragma unroll
    for (int mi = 0; mi < 4; mi++)
#pragma unroll
      for (int nj = 0; nj < 4; nj++)
        acc[mi][nj] = __builtin_amdgcn_mfma_f32_16x16x32_bf16(a[mi], b[nj], acc[mi][nj], 0, 0, 0);
  }

  // ---- epilogue: bias -> fp32 C-tile in LDS -> coalesced float4 stores
  __syncthreads();
#pragma unroll
  for (int nj = 0; nj < 4; nj++) {
    const int n = wn * 64 + nj * 16 + l15;
    const float bias = bp[n];
#pragma unroll
    for (int mi = 0; mi < 4; mi++) {
#pragma unroll
      for (int r = 0; r < 4; r++) {
        const int m = wm * 64 + mi * 16 + l4 * 4 + r;
        *(float*)(plds + ((m * 512 + n * 4) ^ ((m & 7) << 5))) = acc[mi][nj][r] + bias;
      }
    }
  }
  __syncthreads();

#pragma unroll
  for (int i = 0; i < 16; i++) {
    const int idx = i * 256 + tid;         // 0..4095
    const int m = idx >> 5, c = idx & 31;  // row, float4 chunk
    float4 t = *(const float4*)(plds + ((m * 512 + c * 16) ^ ((m & 7) << 5)));
    *(float4*)(out + (size_t)(m_tile * 128 + m) * DD + c * 4) = t;
  }
}

// ---------------------------------------------------------------------------
extern "C" void kernel_launch(void* const* d_in, const int* in_sizes, int n_in,
                              void* d_out, int out_size, void* d_ws, size_t ws_size,
                              hipStream_t stream) {
  const float* x      = (const float*)d_in[0];
  const float* w_qkv  = (const float*)d_in[1];
  const float* b_qkv  = (const float*)d_in[2];
  const float* w_proj = (const float*)d_in[3];
  const float* b_proj = (const float*)d_in[4];
  float* out = (float*)d_out;

  const size_t per = (size_t)BB * NH * HH * WW * HD;  // 4,194,304 elements
  bf16_t* q  = (bf16_t*)d_ws;
  bf16_t* k  = q + per;
  bf16_t* v  = k + per;
  bf16_t* ao = v + per;   // 32 MB bf16 workspace

  qkv_mfma<<<dim3(256, 3), dim3(256), 0, stream>>>(x, w_qkv, b_qkv, q, k, v);
  attn_mfma<<<dim3(64, NH, BB), dim3(256), 0, stream>>>(q, k, v, ao);
  proj_mfma<<<dim3(256), dim3(256), 0, stream>>>(ao, w_proj, b_proj, out);
}